// Round 1
// baseline (851.885 us; speedup 1.0000x reference)
//
#include <hip/hip_runtime.h>
#include <hip/hip_bf16.h>

// Problem constants (reference: B,S,H,D = 2,2048,32,128)
constexpr int Bc = 2;
constexpr int Sc = 2048;
constexpr int Hc = 32;
constexpr int Dc = 128;

constexpr int BQ = 64;   // query rows per block
constexpr int BK = 64;   // kv rows per tile
// scale (1/sqrt(128)) * log2(e), folded into Q at load; softmax in base-2
constexpr float SCALE_LOG2E = 0.088388347648318f * 1.442695040888963f;

typedef __attribute__((ext_vector_type(8))) short bf16x8;
typedef __attribute__((ext_vector_type(4))) float f32x4;

static __device__ __forceinline__ short f2bf(float f) {
    // round-to-nearest-even f32 -> bf16 (finite inputs only)
    unsigned u = __float_as_uint(f);
    unsigned r = (u + 0x7fffu + ((u >> 16) & 1u)) >> 16;
    return (short)r;
}

__global__ void attn_fwd(const float* __restrict__ qkv,
                         const int* __restrict__ causal_p,
                         float* __restrict__ out)
{
    // heavy q-tiles first for better tail behavior under causal imbalance
    const int qt = (int)(gridDim.x - 1) - (int)blockIdx.x;
    const int bh = blockIdx.y;
    const int b = bh >> 5;    // H = 32
    const int h = bh & 31;
    const int causal = *causal_p;

    const int tid  = threadIdx.x;
    const int w    = tid >> 6;    // wave 0..3
    const int lane = tid & 63;
    const int l15  = lane & 15;
    const int lg   = lane >> 4;   // 0..3

    // K: [64][128] bf16, row stride 136 (272B -> 2-way bank alias on b128 reads, free)
    // V: transposed [128][64] bf16, row stride 72 (144B -> 2-way alias, free)
    // P: per-wave [16][64] bf16, row stride 72
    __shared__ short Ks[64 * 136];
    __shared__ short Vs[128 * 72];
    __shared__ short Ps[4][16 * 72];

    const int q0 = qt * BQ;

    // ---- Q fragments: 16 rows per wave, scaled, bf16 ----
    bf16x8 qf[4];
    {
        const int qrow = q0 + w * 16 + l15;
        const float* qb = qkv + (size_t)(b * Sc + qrow) * (3 * Hc * Dc) + h * Dc;
        #pragma unroll
        for (int dc = 0; dc < 4; ++dc) {
            const float* p = qb + dc * 32 + lg * 8;
            float4 x0 = *(const float4*)(p);
            float4 x1 = *(const float4*)(p + 4);
            bf16x8 q;
            q[0] = f2bf(x0.x * SCALE_LOG2E);
            q[1] = f2bf(x0.y * SCALE_LOG2E);
            q[2] = f2bf(x0.z * SCALE_LOG2E);
            q[3] = f2bf(x0.w * SCALE_LOG2E);
            q[4] = f2bf(x1.x * SCALE_LOG2E);
            q[5] = f2bf(x1.y * SCALE_LOG2E);
            q[6] = f2bf(x1.z * SCALE_LOG2E);
            q[7] = f2bf(x1.w * SCALE_LOG2E);
            qf[dc] = q;
        }
    }

    f32x4 o[8];
    #pragma unroll
    for (int i = 0; i < 8; ++i) o[i] = (f32x4){0.f, 0.f, 0.f, 0.f};
    float mrow[4] = {-1e30f, -1e30f, -1e30f, -1e30f};
    float lrow[4] = {0.f, 0.f, 0.f, 0.f};

    const int nkv = causal ? (qt + 1) : (Sc / BK);

    for (int kt = 0; kt < nkv; ++kt) {
        __syncthreads();   // protect LDS from previous iteration's readers
        // ---- stage K (row-major) and V (transposed) as bf16 ----
        {
            const int krow0 = kt * BK;
            #pragma unroll
            for (int i = 0; i < 8; ++i) {
                const int e   = i * 256 + tid;     // 2048 float4-quads total
                const int row = e >> 5;            // 0..63
                const int col = (e & 31) * 4;      // 0..124
                const float* kp = qkv + (size_t)(b * Sc + krow0 + row) * (3 * Hc * Dc)
                                  + Hc * Dc + h * Dc + col;
                float4 kx = *(const float4*)kp;
                short* kd = &Ks[row * 136 + col];
                kd[0] = f2bf(kx.x); kd[1] = f2bf(kx.y);
                kd[2] = f2bf(kx.z); kd[3] = f2bf(kx.w);
                float4 vx = *(const float4*)(kp + Hc * Dc);
                Vs[(col + 0) * 72 + row] = f2bf(vx.x);
                Vs[(col + 1) * 72 + row] = f2bf(vx.y);
                Vs[(col + 2) * 72 + row] = f2bf(vx.z);
                Vs[(col + 3) * 72 + row] = f2bf(vx.w);
            }
        }
        __syncthreads();

        // ---- S = Q K^T  (4 chunks of 16 keys) ----
        f32x4 s[4];
        #pragma unroll
        for (int kc = 0; kc < 4; ++kc) {
            s[kc] = (f32x4){0.f, 0.f, 0.f, 0.f};
            #pragma unroll
            for (int dc = 0; dc < 4; ++dc) {
                bf16x8 kb = *(const bf16x8*)&Ks[(kc * 16 + l15) * 136 + dc * 32 + lg * 8];
                s[kc] = __builtin_amdgcn_mfma_f32_16x16x32_bf16(qf[dc], kb, s[kc], 0, 0, 0);
            }
        }

        // ---- causal mask on the diagonal tile ----
        if (causal && kt == qt) {
            #pragma unroll
            for (int kc = 0; kc < 4; ++kc) {
                const int kj = kc * 16 + l15;
                #pragma unroll
                for (int r = 0; r < 4; ++r) {
                    const int qi = w * 16 + lg * 4 + r;
                    if (kj > qi) s[kc][r] = -1e30f;
                }
            }
        }

        // ---- online softmax (base-2) ----
        #pragma unroll
        for (int r = 0; r < 4; ++r) {
            float mloc = fmaxf(fmaxf(s[0][r], s[1][r]), fmaxf(s[2][r], s[3][r]));
            #pragma unroll
            for (int off = 1; off < 16; off <<= 1)
                mloc = fmaxf(mloc, __shfl_xor(mloc, off));
            const float mnew  = fmaxf(mrow[r], mloc);
            const float alpha = exp2f(mrow[r] - mnew);
            mrow[r] = mnew;
            float rsum = 0.f;
            #pragma unroll
            for (int kc = 0; kc < 4; ++kc) {
                const float p = exp2f(s[kc][r] - mnew);
                s[kc][r] = p;
                rsum += p;
            }
            #pragma unroll
            for (int off = 1; off < 16; off <<= 1)
                rsum += __shfl_xor(rsum, off);
            lrow[r] = lrow[r] * alpha + rsum;
            #pragma unroll
            for (int dc = 0; dc < 8; ++dc) o[dc][r] *= alpha;
        }

        // ---- P -> LDS (per-wave) to re-layout for MFMA A operand ----
        short* pw = Ps[w];
        #pragma unroll
        for (int kc = 0; kc < 4; ++kc) {
            #pragma unroll
            for (int r = 0; r < 4; ++r)
                pw[(lg * 4 + r) * 72 + kc * 16 + l15] = f2bf(s[kc][r]);
        }

        // ---- O += P V ----
        #pragma unroll
        for (int k2 = 0; k2 < 2; ++k2) {
            bf16x8 pa = *(const bf16x8*)&pw[l15 * 72 + k2 * 32 + lg * 8];
            #pragma unroll
            for (int dc = 0; dc < 8; ++dc) {
                bf16x8 vb = *(const bf16x8*)&Vs[(dc * 16 + l15) * 72 + k2 * 32 + lg * 8];
                o[dc] = __builtin_amdgcn_mfma_f32_16x16x32_bf16(pa, vb, o[dc], 0, 0, 0);
            }
        }
    }

    // ---- epilogue: normalize + store fp32 ----
    float inv[4];
    #pragma unroll
    for (int r = 0; r < 4; ++r) inv[r] = 1.f / lrow[r];
    #pragma unroll
    for (int r = 0; r < 4; ++r) {
        const int qg = q0 + w * 16 + lg * 4 + r;
        float* ob = out + (size_t)(b * Sc + qg) * (Hc * Dc) + h * Dc;
        #pragma unroll
        for (int dc = 0; dc < 8; ++dc)
            ob[dc * 16 + l15] = o[dc][r] * inv[r];
    }
}

extern "C" void kernel_launch(void* const* d_in, const int* in_sizes, int n_in,
                              void* d_out, int out_size, void* d_ws, size_t ws_size,
                              hipStream_t stream) {
    const float* qkv = (const float*)d_in[0];
    const int* causal = (const int*)d_in[1];
    float* out = (float*)d_out;
    dim3 grid(Sc / BQ, Bc * Hc);
    attn_fwd<<<grid, 256, 0, stream>>>(qkv, causal, out);
}

// Round 2
// 448.919 us; speedup vs baseline: 1.8976x; 1.8976x over previous
//
#include <hip/hip_runtime.h>
#include <hip/hip_bf16.h>

// Problem constants (reference: B,S,H,D = 2,2048,32,128)
constexpr int Bc = 2;
constexpr int Sc = 2048;
constexpr int Hc = 32;
constexpr int Dc = 128;
constexpr int QKV_STRIDE = 3 * Hc * Dc;   // floats per (b, s) row: 12288

constexpr int BQ = 64;   // query rows per block
constexpr int BK = 64;   // kv rows per tile
// scale (1/sqrt(128)) * log2(e), folded into Q at load; softmax in base-2
constexpr float SCALE_LOG2E = 0.088388347648318f * 1.442695040888963f;

typedef __attribute__((ext_vector_type(8))) short bf16x8;
typedef __attribute__((ext_vector_type(4))) short bf16x4;
typedef __attribute__((ext_vector_type(4))) float f32x4;

static __device__ __forceinline__ short f2bf(float f) {
    // round-to-nearest-even f32 -> bf16 (finite inputs only)
    unsigned u = __float_as_uint(f);
    unsigned r = (u + 0x7fffu + ((u >> 16) & 1u)) >> 16;
    return (short)r;
}

__global__ __launch_bounds__(256)
void attn_fwd(const float* __restrict__ qkv,
              const int* __restrict__ causal_p,
              float* __restrict__ out)
{
    // heavy q-tiles first for better tail behavior under causal imbalance
    const int qt = (int)(gridDim.x - 1) - (int)blockIdx.x;
    const int bh = blockIdx.y;
    const int b = bh >> 5;    // H = 32
    const int h = bh & 31;
    const int causal = *causal_p;

    const int tid  = threadIdx.x;
    const int w    = tid >> 6;    // wave 0..3
    const int lane = tid & 63;
    const int l15  = lane & 15;
    const int lg   = lane >> 4;   // 0..3

    // K: [64][136] bf16 row-major (272B rows -> 2-way alias on b128 reads, free)
    // V: transposed [128][72] bf16 (Vs[d][k]); staged via per-d b128 writes ->
    //    bank slot = 4*(d&7), 8 slots -> conflict-free at the 8-cycle floor
    // P: per-wave [16][72] bf16
    __shared__ short Ks[64 * 136];
    __shared__ short Vs[128 * 72];
    __shared__ short Ps[4][16 * 72];

    const int q0 = qt * BQ;

    // staging decomposition: 8 k-row groups x 32 d-lanes
    const int kg = tid >> 5;   // 0..7 -> k rows kg*8 .. kg*8+7
    const int dl = tid & 31;   // 0..31

    const float* kplane = qkv + (size_t)b * Sc * QKV_STRIDE + Hc * Dc + h * Dc;

    // ---- Q fragments: 16 rows per wave, scaled, bf16 ----
    bf16x8 qf[4];
    {
        const int qrow = q0 + w * 16 + l15;
        const float* qb = qkv + (size_t)(b * Sc + qrow) * QKV_STRIDE + h * Dc;
        #pragma unroll
        for (int dc = 0; dc < 4; ++dc) {
            const float* p = qb + dc * 32 + lg * 8;
            float4 x0 = *(const float4*)(p);
            float4 x1 = *(const float4*)(p + 4);
            bf16x8 q;
            q[0] = f2bf(x0.x * SCALE_LOG2E);
            q[1] = f2bf(x0.y * SCALE_LOG2E);
            q[2] = f2bf(x0.z * SCALE_LOG2E);
            q[3] = f2bf(x0.w * SCALE_LOG2E);
            q[4] = f2bf(x1.x * SCALE_LOG2E);
            q[5] = f2bf(x1.y * SCALE_LOG2E);
            q[6] = f2bf(x1.z * SCALE_LOG2E);
            q[7] = f2bf(x1.w * SCALE_LOG2E);
            qf[dc] = q;
        }
    }

    f32x4 o[8];
    #pragma unroll
    for (int i = 0; i < 8; ++i) o[i] = (f32x4){0.f, 0.f, 0.f, 0.f};
    float mrow[4] = {-1e30f, -1e30f, -1e30f, -1e30f};
    float lrow[4] = {0.f, 0.f, 0.f, 0.f};

    const int nkv = causal ? (qt + 1) : (Sc / BK);

    // ---- staging registers (tile t+1 in flight during compute of t) ----
    float4 kst[8];        // K[kg*8+j][dl*4 .. +3]
    float  vst[8][4];     // V[kg*8+j][q*32 + dl]

    auto issue = [&](int kt) {
        const float* kb = kplane + (size_t)(kt * BK + kg * 8) * QKV_STRIDE;
        #pragma unroll
        for (int j = 0; j < 8; ++j)
            kst[j] = *(const float4*)(kb + (size_t)j * QKV_STRIDE + dl * 4);
        const float* vb = kb + Hc * Dc;
        #pragma unroll
        for (int j = 0; j < 8; ++j) {
            #pragma unroll
            for (int q = 0; q < 4; ++q)
                vst[j][q] = vb[(size_t)j * QKV_STRIDE + q * 32 + dl];
        }
    };

    auto commit = [&]() {
        #pragma unroll
        for (int j = 0; j < 8; ++j) {
            bf16x4 kk;
            kk[0] = f2bf(kst[j].x); kk[1] = f2bf(kst[j].y);
            kk[2] = f2bf(kst[j].z); kk[3] = f2bf(kst[j].w);
            *(bf16x4*)&Ks[(kg * 8 + j) * 136 + dl * 4] = kk;
        }
        #pragma unroll
        for (int q = 0; q < 4; ++q) {
            bf16x8 vv;
            #pragma unroll
            for (int j = 0; j < 8; ++j) vv[j] = f2bf(vst[j][q]);
            *(bf16x8*)&Vs[(q * 32 + dl) * 72 + kg * 8] = vv;
        }
    };

    issue(0);

    for (int kt = 0; kt < nkv; ++kt) {
        __syncthreads();               // previous tile's LDS readers done
        commit();                      // cvt + conflict-free LDS writes
        if (kt + 1 < nkv) issue(kt + 1);   // next tile's globals fly under compute
        __syncthreads();               // staged tile visible

        // ---- S = Q K^T  (4 chunks of 16 keys) ----
        f32x4 s[4];
        #pragma unroll
        for (int kc = 0; kc < 4; ++kc) {
            s[kc] = (f32x4){0.f, 0.f, 0.f, 0.f};
            #pragma unroll
            for (int dc = 0; dc < 4; ++dc) {
                bf16x8 kb = *(const bf16x8*)&Ks[(kc * 16 + l15) * 136 + dc * 32 + lg * 8];
                s[kc] = __builtin_amdgcn_mfma_f32_16x16x32_bf16(qf[dc], kb, s[kc], 0, 0, 0);
            }
        }

        // ---- causal mask on the diagonal tile ----
        if (causal && kt == qt) {
            #pragma unroll
            for (int kc = 0; kc < 4; ++kc) {
                const int kj = kc * 16 + l15;
                #pragma unroll
                for (int r = 0; r < 4; ++r) {
                    const int qi = w * 16 + lg * 4 + r;
                    if (kj > qi) s[kc][r] = -1e30f;
                }
            }
        }

        // ---- online softmax (base-2) ----
        #pragma unroll
        for (int r = 0; r < 4; ++r) {
            float mloc = fmaxf(fmaxf(s[0][r], s[1][r]), fmaxf(s[2][r], s[3][r]));
            #pragma unroll
            for (int off = 1; off < 16; off <<= 1)
                mloc = fmaxf(mloc, __shfl_xor(mloc, off));
            const float mnew  = fmaxf(mrow[r], mloc);
            const float alpha = exp2f(mrow[r] - mnew);
            mrow[r] = mnew;
            float rsum = 0.f;
            #pragma unroll
            for (int kc = 0; kc < 4; ++kc) {
                const float p = exp2f(s[kc][r] - mnew);
                s[kc][r] = p;
                rsum += p;
            }
            #pragma unroll
            for (int off = 1; off < 16; off <<= 1)
                rsum += __shfl_xor(rsum, off);
            lrow[r] = lrow[r] * alpha + rsum;
            #pragma unroll
            for (int dc = 0; dc < 8; ++dc) o[dc][r] *= alpha;
        }

        // ---- P -> LDS (per-wave) to re-layout for MFMA A operand ----
        short* pw = Ps[w];
        #pragma unroll
        for (int kc = 0; kc < 4; ++kc) {
            #pragma unroll
            for (int r = 0; r < 4; ++r)
                pw[(lg * 4 + r) * 72 + kc * 16 + l15] = f2bf(s[kc][r]);
        }

        // ---- O += P V ----
        #pragma unroll
        for (int k2 = 0; k2 < 2; ++k2) {
            bf16x8 pa = *(const bf16x8*)&pw[l15 * 72 + k2 * 32 + lg * 8];
            #pragma unroll
            for (int dc = 0; dc < 8; ++dc) {
                bf16x8 vb = *(const bf16x8*)&Vs[(dc * 16 + l15) * 72 + k2 * 32 + lg * 8];
                o[dc] = __builtin_amdgcn_mfma_f32_16x16x32_bf16(pa, vb, o[dc], 0, 0, 0);
            }
        }
    }

    // ---- epilogue: normalize + store fp32 ----
    float inv[4];
    #pragma unroll
    for (int r = 0; r < 4; ++r) inv[r] = 1.f / lrow[r];
    #pragma unroll
    for (int r = 0; r < 4; ++r) {
        const int qg = q0 + w * 16 + lg * 4 + r;
        float* ob = out + (size_t)(b * Sc + qg) * (Hc * Dc) + h * Dc;
        #pragma unroll
        for (int dc = 0; dc < 8; ++dc)
            ob[dc * 16 + l15] = o[dc][r] * inv[r];
    }
}

extern "C" void kernel_launch(void* const* d_in, const int* in_sizes, int n_in,
                              void* d_out, int out_size, void* d_ws, size_t ws_size,
                              hipStream_t stream) {
    const float* qkv = (const float*)d_in[0];
    const int* causal = (const int*)d_in[1];
    float* out = (float*)d_out;
    dim3 grid(Sc / BQ, Bc * Hc);
    attn_fwd<<<grid, 256, 0, stream>>>(qkv, causal, out);
}

// Round 3
// 391.996 us; speedup vs baseline: 2.1732x; 1.1452x over previous
//
#include <hip/hip_runtime.h>
#include <hip/hip_bf16.h>

// Problem constants (reference: B,S,H,D = 2,2048,32,128)
constexpr int Bc = 2;
constexpr int Sc = 2048;
constexpr int Hc = 32;
constexpr int Dc = 128;
constexpr int QKV_STRIDE = 3 * Hc * Dc;   // floats per (b, s) row: 12288

constexpr int BQ = 64;   // query rows per block
constexpr int BK = 64;   // kv rows per tile
// scale (1/sqrt(128)) * log2(e), folded into Q at load; softmax in base-2
constexpr float SCALE_LOG2E = 0.088388347648318f * 1.442695040888963f;
constexpr float DEFER_THR = 8.0f;   // T13: skip rescale while max growth <= 2^8

typedef __attribute__((ext_vector_type(8))) short bf16x8;
typedef __attribute__((ext_vector_type(4))) short bf16x4;
typedef __attribute__((ext_vector_type(4))) float f32x4;

static __device__ __forceinline__ short f2bf(float f) {
    // native cast -> compiler pairs these into v_cvt_pk_bf16_f32 (RNE)
    __bf16 h = (__bf16)f;
    return __builtin_bit_cast(short, h);
}

__global__ __launch_bounds__(256)
void attn_fwd(const float* __restrict__ qkv,
              const int* __restrict__ causal_p,
              float* __restrict__ out)
{
    // heavy q-tiles first for better tail behavior under causal imbalance
    const int qt = (int)(gridDim.x - 1) - (int)blockIdx.x;
    const int bh = blockIdx.y;
    const int b = bh >> 5;    // H = 32
    const int h = bh & 31;
    const int causal = *causal_p;

    const int tid  = threadIdx.x;
    const int w    = tid >> 6;    // wave 0..3
    const int lane = tid & 63;
    const int l15  = lane & 15;
    const int lg   = lane >> 4;   // 0..3

    // K: [64][136] bf16 row-major (272B rows -> 2-way alias on b128 reads, free)
    // V: transposed [128][72] bf16 (Vs[d][k]); staged via per-d b128 writes
    // P: per-wave [16][72] bf16
    __shared__ short Ks[64 * 136];
    __shared__ short Vs[128 * 72];
    __shared__ short Ps[4][16 * 72];

    const int q0 = qt * BQ;

    // staging decomposition: 8 k-row groups x 32 d-lanes
    const int kg = tid >> 5;   // 0..7 -> k rows kg*8 .. kg*8+7
    const int dl = tid & 31;   // 0..31

    const float* kplane = qkv + (size_t)b * Sc * QKV_STRIDE + Hc * Dc + h * Dc;

    // ---- Q fragments: 16 rows per wave, scaled, bf16 ----
    bf16x8 qf[4];
    {
        const int qrow = q0 + w * 16 + l15;
        const float* qb = qkv + (size_t)(b * Sc + qrow) * QKV_STRIDE + h * Dc;
        #pragma unroll
        for (int dc = 0; dc < 4; ++dc) {
            const float* p = qb + dc * 32 + lg * 8;
            float4 x0 = *(const float4*)(p);
            float4 x1 = *(const float4*)(p + 4);
            bf16x8 q;
            q[0] = f2bf(x0.x * SCALE_LOG2E);
            q[1] = f2bf(x0.y * SCALE_LOG2E);
            q[2] = f2bf(x0.z * SCALE_LOG2E);
            q[3] = f2bf(x0.w * SCALE_LOG2E);
            q[4] = f2bf(x1.x * SCALE_LOG2E);
            q[5] = f2bf(x1.y * SCALE_LOG2E);
            q[6] = f2bf(x1.z * SCALE_LOG2E);
            q[7] = f2bf(x1.w * SCALE_LOG2E);
            qf[dc] = q;
        }
    }

    f32x4 o[8];
    #pragma unroll
    for (int i = 0; i < 8; ++i) o[i] = (f32x4){0.f, 0.f, 0.f, 0.f};
    float mrow[4] = {-1e30f, -1e30f, -1e30f, -1e30f};
    float lrow[4] = {0.f, 0.f, 0.f, 0.f};

    const int nkv = causal ? (qt + 1) : (Sc / BK);

    // ---- staging registers (tile t+1 in flight during compute of t) ----
    float4 kst[8];        // K[kg*8+j][dl*4 .. +3]
    float  vst[8][4];     // V[kg*8+j][q*32 + dl]

    auto issue = [&](int kt) {
        const float* kb = kplane + (size_t)(kt * BK + kg * 8) * QKV_STRIDE;
        #pragma unroll
        for (int j = 0; j < 8; ++j)
            kst[j] = *(const float4*)(kb + (size_t)j * QKV_STRIDE + dl * 4);
        const float* vb = kb + Hc * Dc;
        #pragma unroll
        for (int j = 0; j < 8; ++j) {
            #pragma unroll
            for (int q = 0; q < 4; ++q)
                vst[j][q] = vb[(size_t)j * QKV_STRIDE + q * 32 + dl];
        }
    };

    auto commit = [&]() {
        #pragma unroll
        for (int j = 0; j < 8; ++j) {
            bf16x4 kk;
            kk[0] = f2bf(kst[j].x); kk[1] = f2bf(kst[j].y);
            kk[2] = f2bf(kst[j].z); kk[3] = f2bf(kst[j].w);
            *(bf16x4*)&Ks[(kg * 8 + j) * 136 + dl * 4] = kk;
        }
        #pragma unroll
        for (int q = 0; q < 4; ++q) {
            bf16x8 vv;
            #pragma unroll
            for (int j = 0; j < 8; ++j) vv[j] = f2bf(vst[j][q]);
            *(bf16x8*)&Vs[(q * 32 + dl) * 72 + kg * 8] = vv;
        }
    };

    issue(0);

    for (int kt = 0; kt < nkv; ++kt) {
        __syncthreads();               // previous tile's LDS readers done
        commit();                      // cvt_pk + conflict-free LDS writes
        if (kt + 1 < nkv) issue(kt + 1);   // next tile's globals fly under compute
        __syncthreads();               // staged tile visible

        // ---- S = Q K^T  (4 chunks of 16 keys) ----
        f32x4 s[4];
        __builtin_amdgcn_s_setprio(1);
        #pragma unroll
        for (int kc = 0; kc < 4; ++kc) {
            s[kc] = (f32x4){0.f, 0.f, 0.f, 0.f};
            #pragma unroll
            for (int dc = 0; dc < 4; ++dc) {
                bf16x8 kb = *(const bf16x8*)&Ks[(kc * 16 + l15) * 136 + dc * 32 + lg * 8];
                s[kc] = __builtin_amdgcn_mfma_f32_16x16x32_bf16(qf[dc], kb, s[kc], 0, 0, 0);
            }
        }
        __builtin_amdgcn_s_setprio(0);

        // ---- causal mask on the diagonal tile ----
        if (causal && kt == qt) {
            #pragma unroll
            for (int kc = 0; kc < 4; ++kc) {
                const int kj = kc * 16 + l15;
                #pragma unroll
                for (int r = 0; r < 4; ++r) {
                    const int qi = w * 16 + lg * 4 + r;
                    if (kj > qi) s[kc][r] = -1e30f;
                }
            }
        }

        // ---- online softmax (base-2), T13 defer-max ----
        float mloc[4];
        #pragma unroll
        for (int r = 0; r < 4; ++r) {
            float m = fmaxf(fmaxf(s[0][r], s[1][r]), fmaxf(s[2][r], s[3][r]));
            #pragma unroll
            for (int off = 1; off < 16; off <<= 1)
                m = fmaxf(m, __shfl_xor(m, off));
            mloc[r] = m;
        }
        const bool grow = (mloc[0] > mrow[0] + DEFER_THR) ||
                          (mloc[1] > mrow[1] + DEFER_THR) ||
                          (mloc[2] > mrow[2] + DEFER_THR) ||
                          (mloc[3] > mrow[3] + DEFER_THR);
        if (__any(grow)) {
            #pragma unroll
            for (int r = 0; r < 4; ++r) {
                const float mnew  = fmaxf(mrow[r], mloc[r]);
                const float alpha = __builtin_amdgcn_exp2f(mrow[r] - mnew);
                mrow[r] = mnew;
                lrow[r] *= alpha;
                #pragma unroll
                for (int dc = 0; dc < 8; ++dc) o[dc][r] *= alpha;
            }
        }
        #pragma unroll
        for (int r = 0; r < 4; ++r) {
            float rsum = 0.f;
            #pragma unroll
            for (int kc = 0; kc < 4; ++kc) {
                const float p = __builtin_amdgcn_exp2f(s[kc][r] - mrow[r]);
                s[kc][r] = p;
                rsum += p;
            }
            #pragma unroll
            for (int off = 1; off < 16; off <<= 1)
                rsum += __shfl_xor(rsum, off);
            lrow[r] += rsum;
        }

        // ---- P -> LDS (per-wave) to re-layout for MFMA A operand ----
        short* pw = Ps[w];
        #pragma unroll
        for (int kc = 0; kc < 4; ++kc) {
            #pragma unroll
            for (int r = 0; r < 4; ++r)
                pw[(lg * 4 + r) * 72 + kc * 16 + l15] = f2bf(s[kc][r]);
        }

        // ---- O += P V ----
        __builtin_amdgcn_s_setprio(1);
        #pragma unroll
        for (int k2 = 0; k2 < 2; ++k2) {
            bf16x8 pa = *(const bf16x8*)&pw[l15 * 72 + k2 * 32 + lg * 8];
            #pragma unroll
            for (int dc = 0; dc < 8; ++dc) {
                bf16x8 vb = *(const bf16x8*)&Vs[(dc * 16 + l15) * 72 + k2 * 32 + lg * 8];
                o[dc] = __builtin_amdgcn_mfma_f32_16x16x32_bf16(pa, vb, o[dc], 0, 0, 0);
            }
        }
        __builtin_amdgcn_s_setprio(0);
    }

    // ---- epilogue: normalize + store fp32 ----
    float inv[4];
    #pragma unroll
    for (int r = 0; r < 4; ++r) inv[r] = 1.f / lrow[r];
    #pragma unroll
    for (int r = 0; r < 4; ++r) {
        const int qg = q0 + w * 16 + lg * 4 + r;
        float* ob = out + (size_t)(b * Sc + qg) * (Hc * Dc) + h * Dc;
        #pragma unroll
        for (int dc = 0; dc < 8; ++dc)
            ob[dc * 16 + l15] = o[dc][r] * inv[r];
    }
}

extern "C" void kernel_launch(void* const* d_in, const int* in_sizes, int n_in,
                              void* d_out, int out_size, void* d_ws, size_t ws_size,
                              hipStream_t stream) {
    const float* qkv = (const float*)d_in[0];
    const int* causal = (const int*)d_in[1];
    float* out = (float*)d_out;
    dim3 grid(Sc / BQ, Bc * Hc);
    attn_fwd<<<grid, 256, 0, stream>>>(qkv, causal, out);
}